// Round 1
// baseline (3554.558 us; speedup 1.0000x reference)
//
#include <hip/hip_runtime.h>
#include <cstdint>

#define N_NODES 50000
#define IN_DIM 256
#define H_HEADS 8
#define D_HEAD 64
#define HD 512
#define OUT_DIM 64
#define M_PATHS 2
#define E_EDGES 800000
#define SEM_HID 128
#define NEG_SLOPE 0.2f

// ---- float <-> order-preserving uint encoding (for atomic float max) ----
__device__ __forceinline__ unsigned enc_f(float f) {
  unsigned b = __float_as_uint(f);
  return (b & 0x80000000u) ? ~b : (b | 0x80000000u);
}
__device__ __forceinline__ float dec_f(unsigned u) {
  unsigned b = (u & 0x80000000u) ? (u ^ 0x80000000u) : ~u;
  return __uint_as_float(b);
}
#define ENC_NEG_INF 0x007FFFFFu  // enc(-inf)

__device__ __forceinline__ float eluf(float x) {
  return x > 0.f ? x : (expf(x) - 1.f);
}
__device__ __forceinline__ float lrelu(float x) {
  return x > 0.f ? x : NEG_SLOPE * x;
}

// ---- init per-metapath accumulators ----
__global__ void k_init(unsigned* __restrict__ mxu, float* __restrict__ den,
                       int* __restrict__ deg, int* __restrict__ cur) {
  int i = blockIdx.x * blockDim.x + threadIdx.x;
  if (i < N_NODES * H_HEADS) { mxu[i] = ENC_NEG_INF; den[i] = 0.f; }
  if (i < N_NODES) { deg[i] = 0; cur[i] = 0; }
}

// ---- fp32 GEMM: C[N,512] = A[N,256] @ B[256,512], 64x64x16 tile ----
__global__ __launch_bounds__(256) void k_gemm(const float* __restrict__ A,
                                              const float* __restrict__ B,
                                              float* __restrict__ C) {
  __shared__ float As[16][65];
  __shared__ float Bs[16][65];
  const int tid = threadIdx.x;
  const int row0 = blockIdx.x * 64;
  const int col0 = blockIdx.y * 64;
  const int tx = tid & 15, ty = tid >> 4;
  const int arow = tid >> 2, acol = (tid & 3) << 2;
  const int brow = tid >> 4, bcol = (tid & 15) << 2;
  const int grow = row0 + arow;
  float acc[4][4] = {};
  for (int k0 = 0; k0 < IN_DIM; k0 += 16) {
    float4 a4 = make_float4(0.f, 0.f, 0.f, 0.f);
    if (grow < N_NODES) a4 = *(const float4*)&A[(size_t)grow * IN_DIM + k0 + acol];
    As[acol + 0][arow] = a4.x; As[acol + 1][arow] = a4.y;
    As[acol + 2][arow] = a4.z; As[acol + 3][arow] = a4.w;
    float4 b4 = *(const float4*)&B[(size_t)(k0 + brow) * HD + col0 + bcol];
    Bs[brow][bcol + 0] = b4.x; Bs[brow][bcol + 1] = b4.y;
    Bs[brow][bcol + 2] = b4.z; Bs[brow][bcol + 3] = b4.w;
    __syncthreads();
#pragma unroll
    for (int k = 0; k < 16; ++k) {
      float a[4], b[4];
#pragma unroll
      for (int i = 0; i < 4; ++i) a[i] = As[k][ty * 4 + i];
#pragma unroll
      for (int j = 0; j < 4; ++j) b[j] = Bs[k][tx * 4 + j];
#pragma unroll
      for (int i = 0; i < 4; ++i)
#pragma unroll
        for (int j = 0; j < 4; ++j) acc[i][j] += a[i] * b[j];
    }
    __syncthreads();
  }
#pragma unroll
  for (int i = 0; i < 4; ++i) {
    int r = row0 + ty * 4 + i;
    if (r < N_NODES) {
      float4 v = make_float4(acc[i][0], acc[i][1], acc[i][2], acc[i][3]);
      *(float4*)&C[(size_t)r * HD + col0 + tx * 4] = v;
    }
  }
}

// ---- el/er per (node, head) ----
__global__ void k_elr(const float* __restrict__ feat, const float* __restrict__ al,
                      const float* __restrict__ ar, float* __restrict__ el,
                      float* __restrict__ er) {
  int gid = blockIdx.x * blockDim.x + threadIdx.x;
  if (gid >= N_NODES * H_HEADS) return;
  int n = gid >> 3, h = gid & 7;
  const float4* f4 = (const float4*)&feat[(size_t)n * HD + h * D_HEAD];
  const float4* a4 = (const float4*)&al[h * D_HEAD];
  const float4* r4 = (const float4*)&ar[h * D_HEAD];
  float sl = 0.f, sr = 0.f;
#pragma unroll
  for (int k = 0; k < 16; ++k) {
    float4 f = f4[k], a = a4[k], r = r4[k];
    sl += f.x * a.x + f.y * a.y + f.z * a.z + f.w * a.w;
    sr += f.x * r.x + f.y * r.y + f.z * r.z + f.w * r.w;
  }
  el[gid] = sl;
  er[gid] = sr;
}

// ---- edge pass 1: e = leaky(el[src]+er[dst]); segment max; degree ----
__global__ void k_edge_max(const int* __restrict__ src, const int* __restrict__ dst,
                           const float* __restrict__ el, const float* __restrict__ er,
                           float* __restrict__ ebuf, unsigned* __restrict__ mxu,
                           int* __restrict__ deg) {
  int e = blockIdx.x * blockDim.x + threadIdx.x;
  if (e >= E_EDGES) return;
  int s = src[e], d = dst[e];
  atomicAdd(&deg[d], 1);
  float4 l0 = *(const float4*)&el[s * 8], l1 = *(const float4*)&el[s * 8 + 4];
  float4 r0 = *(const float4*)&er[d * 8], r1 = *(const float4*)&er[d * 8 + 4];
  float v[8];
  v[0] = lrelu(l0.x + r0.x); v[1] = lrelu(l0.y + r0.y);
  v[2] = lrelu(l0.z + r0.z); v[3] = lrelu(l0.w + r0.w);
  v[4] = lrelu(l1.x + r1.x); v[5] = lrelu(l1.y + r1.y);
  v[6] = lrelu(l1.z + r1.z); v[7] = lrelu(l1.w + r1.w);
  *(float4*)&ebuf[(size_t)e * 8]     = make_float4(v[0], v[1], v[2], v[3]);
  *(float4*)&ebuf[(size_t)e * 8 + 4] = make_float4(v[4], v[5], v[6], v[7]);
#pragma unroll
  for (int h = 0; h < 8; ++h) atomicMax(&mxu[d * 8 + h], enc_f(v[h]));
}

// ---- edge pass 2: ex = exp(e - m[dst]); segment sum ----
__global__ void k_edge_exp(const int* __restrict__ dst, const unsigned* __restrict__ mxu,
                           float* __restrict__ ebuf, float* __restrict__ den) {
  int e = blockIdx.x * blockDim.x + threadIdx.x;
  if (e >= E_EDGES) return;
  int d = dst[e];
  float4 e0 = *(const float4*)&ebuf[(size_t)e * 8];
  float4 e1 = *(const float4*)&ebuf[(size_t)e * 8 + 4];
  float ex[8];
  ex[0] = expf(e0.x - dec_f(mxu[d * 8 + 0]));
  ex[1] = expf(e0.y - dec_f(mxu[d * 8 + 1]));
  ex[2] = expf(e0.z - dec_f(mxu[d * 8 + 2]));
  ex[3] = expf(e0.w - dec_f(mxu[d * 8 + 3]));
  ex[4] = expf(e1.x - dec_f(mxu[d * 8 + 4]));
  ex[5] = expf(e1.y - dec_f(mxu[d * 8 + 5]));
  ex[6] = expf(e1.z - dec_f(mxu[d * 8 + 6]));
  ex[7] = expf(e1.w - dec_f(mxu[d * 8 + 7]));
  *(float4*)&ebuf[(size_t)e * 8]     = make_float4(ex[0], ex[1], ex[2], ex[3]);
  *(float4*)&ebuf[(size_t)e * 8 + 4] = make_float4(ex[4], ex[5], ex[6], ex[7]);
#pragma unroll
  for (int h = 0; h < 8; ++h) atomicAdd(&den[d * 8 + h], ex[h]);
}

// ---- exclusive prefix sum over deg[N] -> rowptr[N+1], single block ----
__global__ void k_scan(const int* __restrict__ deg, int* __restrict__ rowptr) {
  __shared__ int lds[1024];
  __shared__ int carry;
  const int tid = threadIdx.x;
  if (tid == 0) carry = 0;
  __syncthreads();
  for (int base = 0; base < N_NODES; base += 1024) {
    int i = base + tid;
    int v = (i < N_NODES) ? deg[i] : 0;
    lds[tid] = v;
    __syncthreads();
    for (int off = 1; off < 1024; off <<= 1) {
      int t = (tid >= off) ? lds[tid - off] : 0;
      __syncthreads();
      lds[tid] += t;
      __syncthreads();
    }
    if (i < N_NODES) rowptr[i] = carry + lds[tid] - v;
    int total = lds[1023];
    __syncthreads();
    if (tid == 0) carry += total;
    __syncthreads();
  }
  if (tid == 0) rowptr[N_NODES] = carry;
}

// ---- scatter edge ids into CSR slots ----
__global__ void k_scatter(const int* __restrict__ dst, const int* __restrict__ rowptr,
                          int* __restrict__ cur, int* __restrict__ csr) {
  int e = blockIdx.x * blockDim.x + threadIdx.x;
  if (e >= E_EDGES) return;
  int d = dst[e];
  int p = atomicAdd(&cur[d], 1);
  csr[rowptr[d] + p] = e;
}

// ---- per-node: aggregate + ELU + semantic partials + y = z@Wout ----
__global__ __launch_bounds__(128) void k_node(
    const float* __restrict__ feat, const float* __restrict__ ebuf,
    const int* __restrict__ csr, const int* __restrict__ rowptr,
    const int* __restrict__ src, const float* __restrict__ den,
    const float* __restrict__ bg, const float* __restrict__ W1,
    const float* __restrict__ b1, const float* __restrict__ qv,
    const float* __restrict__ Wout, float* __restrict__ y,
    float* __restrict__ wpart) {
  __shared__ float zs[HD];
  __shared__ float red[128];
  const int n = blockIdx.x;
  const int tid = threadIdx.x;
  const int h = tid >> 4;  // head of this thread's 4 feature columns
  const int r0 = rowptr[n], r1 = rowptr[n + 1];
  float ax = 0.f, ay = 0.f, az = 0.f, aw = 0.f;
  const float4* feat4 = (const float4*)feat;
  for (int idx = r0; idx < r1; ++idx) {
    const int eid = csr[idx];
    const int s = src[eid];
    const float ex = ebuf[(size_t)eid * 8 + h];
    const float4 f = feat4[(size_t)s * 128 + tid];
    ax += ex * f.x; ay += ex * f.y; az += ex * f.z; aw += ex * f.w;
  }
  const float ds = 1.f / fmaxf(den[n * 8 + h], 1e-9f);
  const float4 b = ((const float4*)bg)[tid];
  zs[tid * 4 + 0] = eluf(ax * ds + b.x);
  zs[tid * 4 + 1] = eluf(ay * ds + b.y);
  zs[tid * 4 + 2] = eluf(az * ds + b.z);
  zs[tid * 4 + 3] = eluf(aw * ds + b.w);
  __syncthreads();
  // semantic attention hidden unit per thread (128 = SEM_HID)
  float h0 = 0.f, h1 = 0.f, h2 = 0.f, h3 = 0.f;
  for (int k = 0; k < HD; k += 4) {
    h0 += zs[k + 0] * W1[(k + 0) * SEM_HID + tid];
    h1 += zs[k + 1] * W1[(k + 1) * SEM_HID + tid];
    h2 += zs[k + 2] * W1[(k + 2) * SEM_HID + tid];
    h3 += zs[k + 3] * W1[(k + 3) * SEM_HID + tid];
  }
  float hv = tanhf(b1[tid] + ((h0 + h1) + (h2 + h3)));
  red[tid] = hv * qv[tid];
  __syncthreads();
#pragma unroll
  for (int off = 64; off > 0; off >>= 1) {
    if (tid < off) red[tid] += red[tid + off];
    __syncthreads();
  }
  if (tid == 0) atomicAdd(&wpart[n & 255], red[0]);
  // y row: 64 outputs, 2 threads each (split K range)
  const int j = tid & 63;
  const int kb = (tid >> 6) * 256;
  float y0 = 0.f, y1 = 0.f, y2 = 0.f, y3 = 0.f;
  for (int k = kb; k < kb + 256; k += 4) {
    y0 += zs[k + 0] * Wout[(k + 0) * OUT_DIM + j];
    y1 += zs[k + 1] * Wout[(k + 1) * OUT_DIM + j];
    y2 += zs[k + 2] * Wout[(k + 2) * OUT_DIM + j];
    y3 += zs[k + 3] * Wout[(k + 3) * OUT_DIM + j];
  }
  red[tid] = (y0 + y1) + (y2 + y3);
  __syncthreads();
  if (tid < 64) y[(size_t)n * OUT_DIM + tid] = red[tid] + red[tid + 64];
}

// ---- reduce semantic partials -> beta[2] ----
__global__ void k_beta(const float* __restrict__ wpart, float* __restrict__ beta) {
  __shared__ float red[256];
  __shared__ float w0s;
  const int tid = threadIdx.x;
  red[tid] = wpart[tid];
  __syncthreads();
#pragma unroll
  for (int off = 128; off > 0; off >>= 1) {
    if (tid < off) red[tid] += red[tid + off];
    __syncthreads();
  }
  if (tid == 0) w0s = red[0];
  __syncthreads();
  red[tid] = wpart[256 + tid];
  __syncthreads();
#pragma unroll
  for (int off = 128; off > 0; off >>= 1) {
    if (tid < off) red[tid] += red[tid + off];
    __syncthreads();
  }
  if (tid == 0) {
    float w0 = w0s / (float)N_NODES;
    float w1 = red[0] / (float)N_NODES;
    float mx = fmaxf(w0, w1);
    float e0 = expf(w0 - mx), e1 = expf(w1 - mx);
    float inv = 1.f / (e0 + e1);
    beta[0] = e0 * inv;
    beta[1] = e1 * inv;
  }
}

// ---- final: out = beta0*y0 + beta1*y1 + bout ----
__global__ void k_final(const float* __restrict__ y, const float* __restrict__ beta,
                        const float* __restrict__ bout, float* __restrict__ out) {
  int i = blockIdx.x * blockDim.x + threadIdx.x;
  if (i >= N_NODES * OUT_DIM) return;
  float b0 = beta[0], b1 = beta[1];
  out[i] = b0 * y[i] + b1 * y[(size_t)N_NODES * OUT_DIM + i] + bout[i & 63];
}

extern "C" void kernel_launch(void* const* d_in, const int* in_sizes, int n_in,
                              void* d_out, int out_size, void* d_ws, size_t ws_size,
                              hipStream_t stream) {
  const float* x    = (const float*)d_in[0];
  const int*   src  = (const int*)d_in[1];
  const int*   dst  = (const int*)d_in[2];
  const float* Wg   = (const float*)d_in[3];
  const float* al   = (const float*)d_in[4];
  const float* ar   = (const float*)d_in[5];
  const float* bg   = (const float*)d_in[6];
  const float* W1   = (const float*)d_in[7];
  const float* b1   = (const float*)d_in[8];
  const float* q    = (const float*)d_in[9];
  const float* Wout = (const float*)d_in[10];
  const float* bout = (const float*)d_in[11];
  float* out = (float*)d_out;

  // workspace layout (floats), all offsets multiple of 16 floats (64B)
  float* ws      = (float*)d_ws;
  float* feat    = ws;                              // 25,600,000
  float* ebuf    = feat + 25600000;                 //  6,400,000
  float* el      = ebuf + 6400000;                  //    400,000
  float* er      = el + 400000;                     //    400,000
  float* den     = er + 400000;                     //    400,000
  unsigned* mxu  = (unsigned*)(den + 400000);       //    400,000
  int* deg       = (int*)(mxu + 400000);            //     50,048
  int* cur       = deg + 50048;                     //     50,048
  int* rowptr    = cur + 50048;                     //     50,048
  int* csr       = rowptr + 50048;                  //    800,000
  float* y       = (float*)(csr + 800000);          //  6,400,000
  float* wpart   = y + 6400000;                     //        512
  float* beta    = wpart + 512;                     //         16

  hipMemsetAsync(wpart, 0, 512 * sizeof(float), stream);

  for (int m = 0; m < M_PATHS; ++m) {
    const int* srcm = src + (size_t)m * E_EDGES;
    const int* dstm = dst + (size_t)m * E_EDGES;
    k_init<<<1563, 256, 0, stream>>>(mxu, den, deg, cur);
    dim3 gg(782, 8);
    k_gemm<<<gg, 256, 0, stream>>>(x, Wg + (size_t)m * IN_DIM * HD, feat);
    k_elr<<<1563, 256, 0, stream>>>(feat, al + m * HD, ar + m * HD, el, er);
    k_edge_max<<<3125, 256, 0, stream>>>(srcm, dstm, el, er, ebuf, mxu, deg);
    k_edge_exp<<<3125, 256, 0, stream>>>(dstm, mxu, ebuf, den);
    k_scan<<<1, 1024, 0, stream>>>(deg, rowptr);
    k_scatter<<<3125, 256, 0, stream>>>(dstm, rowptr, cur, csr);
    k_node<<<50000, 128, 0, stream>>>(feat, ebuf, csr, rowptr, srcm, den,
                                      bg + m * HD, W1, b1, q, Wout,
                                      y + (size_t)m * N_NODES * OUT_DIM,
                                      wpart + m * 256);
  }
  k_beta<<<1, 256, 0, stream>>>(wpart, beta);
  int nfin = (N_NODES * OUT_DIM + 255) / 256;
  k_final<<<nfin, 256, 0, stream>>>(y, beta, bout, out);
}

// Round 2
// 2161.134 us; speedup vs baseline: 1.6448x; 1.6448x over previous
//
#include <hip/hip_runtime.h>
#include <cstdint>

#define N_NODES 50000
#define IN_DIM 256
#define H_HEADS 8
#define D_HEAD 64
#define HD 512
#define OUT_DIM 64
#define M_PATHS 2
#define E_EDGES 800000
#define SEM_HID 128
#define NEG_SLOPE 0.2f

typedef __attribute__((ext_vector_type(8))) short bf16x8;
typedef __attribute__((ext_vector_type(4))) float f32x4;
typedef __attribute__((ext_vector_type(8))) unsigned short u16x8;

// ---- bf16 helpers ----
__device__ __forceinline__ float b2f(unsigned short u) {
  return __uint_as_float(((unsigned)u) << 16);
}
__device__ __forceinline__ unsigned short f2b(float f) {
  unsigned u = __float_as_uint(f);
  unsigned r = (u + 0x7fffu + ((u >> 16) & 1u)) >> 16;
  return (unsigned short)r;
}

// ---- float <-> order-preserving uint encoding (for atomic float max) ----
__device__ __forceinline__ unsigned enc_f(float f) {
  unsigned b = __float_as_uint(f);
  return (b & 0x80000000u) ? ~b : (b | 0x80000000u);
}
__device__ __forceinline__ float dec_f(unsigned u) {
  unsigned b = (u & 0x80000000u) ? (u ^ 0x80000000u) : ~u;
  return __uint_as_float(b);
}
#define ENC_NEG_INF 0x007FFFFFu

__device__ __forceinline__ float eluf(float x) {
  return x > 0.f ? x : (expf(x) - 1.f);
}
__device__ __forceinline__ float lrelu(float x) {
  return x > 0.f ? x : NEG_SLOPE * x;
}

// ---- weight conversion + transpose to bf16 [col][k] layouts ----
__global__ void k_prep(const float* __restrict__ Wg, const float* __restrict__ W1,
                       const float* __restrict__ Wout, unsigned short* __restrict__ WgbT,
                       unsigned short* __restrict__ W1T, unsigned short* __restrict__ WoutT) {
  int gid = blockIdx.x * blockDim.x + threadIdx.x;
  if (gid < 262144) {
    int m = gid >> 17, r = gid & 131071, n = r >> 8, k = r & 255;
    WgbT[(size_t)m * 131072 + n * 256 + k] = f2b(Wg[(size_t)m * 131072 + k * 512 + n]);
  } else if (gid < 327680) {
    int r = gid - 262144; int c = r >> 9, k = r & 511;
    W1T[c * 512 + k] = f2b(W1[k * 128 + c]);
  } else if (gid < 360448) {
    int r = gid - 327680; int c = r >> 9, k = r & 511;
    WoutT[c * 512 + k] = f2b(Wout[k * 64 + c]);
  }
}

// ---- init per-metapath accumulators ----
__global__ void k_init(unsigned* __restrict__ mxu, float* __restrict__ den,
                       int* __restrict__ deg, int* __restrict__ cur) {
  int i = blockIdx.x * blockDim.x + threadIdx.x;
  if (i < N_NODES * H_HEADS) { mxu[i] = ENC_NEG_INF; den[i] = 0.f; }
  if (i < N_NODES) { deg[i] = 0; cur[i] = 0; }
}

// ---- GEMM 1: featb[N,512](bf16) = x[N,256](fp32, converted) @ Wg ----
// A staged with on-the-fly fp32->bf16; B from pre-transposed WgbT[col][k].
__global__ __launch_bounds__(256) void k_gemm_feat(const float* __restrict__ A,
                                                   const unsigned short* __restrict__ BT,
                                                   unsigned short* __restrict__ C) {
  __shared__ __align__(16) unsigned short As[64][72];
  __shared__ __align__(16) unsigned short Bs[64][72];
  const int tid = threadIdx.x;
  const int r0 = blockIdx.x * 64, c0 = blockIdx.y * 64;
  const int w = tid >> 6, lane = tid & 63;
  const int cl = lane & 15, kg = lane >> 4;
  f32x4 acc[4] = {};
  for (int k0 = 0; k0 < IN_DIM; k0 += 64) {
#pragma unroll
    for (int p = 0; p < 2; ++p) {
      int c = tid + p * 256;
      int row = c >> 3, ko = (c & 7) * 8;
      u16x8 v;
      if (r0 + row < N_NODES) {
        const float4* g = (const float4*)&A[(size_t)(r0 + row) * IN_DIM + k0 + ko];
        float4 g0 = g[0], g1 = g[1];
        v[0] = f2b(g0.x); v[1] = f2b(g0.y); v[2] = f2b(g0.z); v[3] = f2b(g0.w);
        v[4] = f2b(g1.x); v[5] = f2b(g1.y); v[6] = f2b(g1.z); v[7] = f2b(g1.w);
      } else {
        v = (u16x8)(unsigned short)0;
      }
      *(u16x8*)&As[row][ko] = v;
      *(u16x8*)&Bs[row][ko] = *(const u16x8*)&BT[(size_t)(c0 + row) * IN_DIM + k0 + ko];
    }
    __syncthreads();
#pragma unroll
    for (int kk = 0; kk < 64; kk += 32) {
      bf16x8 a = *(const bf16x8*)&As[w * 16 + cl][kk + kg * 8];
#pragma unroll
      for (int ct = 0; ct < 4; ++ct) {
        bf16x8 b = *(const bf16x8*)&Bs[ct * 16 + cl][kk + kg * 8];
        acc[ct] = __builtin_amdgcn_mfma_f32_16x16x32_bf16(a, b, acc[ct], 0, 0, 0);
      }
    }
    __syncthreads();
  }
#pragma unroll
  for (int ct = 0; ct < 4; ++ct)
#pragma unroll
    for (int reg = 0; reg < 4; ++reg) {
      int row = r0 + w * 16 + kg * 4 + reg;
      if (row < N_NODES) C[(size_t)row * HD + c0 + ct * 16 + cl] = f2b(acc[ct][reg]);
    }
}

// ---- el/er per (node, head) from bf16 feat ----
__global__ void k_elr(const unsigned short* __restrict__ featb, const float* __restrict__ al,
                      const float* __restrict__ ar, float* __restrict__ el,
                      float* __restrict__ er) {
  int gid = blockIdx.x * blockDim.x + threadIdx.x;
  if (gid >= N_NODES * H_HEADS) return;
  int n = gid >> 3, h = gid & 7;
  const u16x8* f8 = (const u16x8*)&featb[(size_t)n * HD + h * D_HEAD];
  float sl = 0.f, sr = 0.f;
#pragma unroll
  for (int c = 0; c < 8; ++c) {
    u16x8 f = f8[c];
#pragma unroll
    for (int j = 0; j < 8; ++j) {
      float v = b2f(f[j]);
      sl += v * al[h * D_HEAD + c * 8 + j];
      sr += v * ar[h * D_HEAD + c * 8 + j];
    }
  }
  el[gid] = sl;
  er[gid] = sr;
}

// ---- edge pass 1: e = leaky(el[src]+er[dst]) (bf16 store); segment max; degree ----
__global__ void k_edge_max(const int* __restrict__ src, const int* __restrict__ dst,
                           const float* __restrict__ el, const float* __restrict__ er,
                           unsigned short* __restrict__ ebuf, unsigned* __restrict__ mxu,
                           int* __restrict__ deg) {
  int e = blockIdx.x * blockDim.x + threadIdx.x;
  if (e >= E_EDGES) return;
  int s = src[e], d = dst[e];
  atomicAdd(&deg[d], 1);
  float4 l0 = *(const float4*)&el[s * 8], l1 = *(const float4*)&el[s * 8 + 4];
  float4 r0 = *(const float4*)&er[d * 8], r1 = *(const float4*)&er[d * 8 + 4];
  float v[8];
  v[0] = lrelu(l0.x + r0.x); v[1] = lrelu(l0.y + r0.y);
  v[2] = lrelu(l0.z + r0.z); v[3] = lrelu(l0.w + r0.w);
  v[4] = lrelu(l1.x + r1.x); v[5] = lrelu(l1.y + r1.y);
  v[6] = lrelu(l1.z + r1.z); v[7] = lrelu(l1.w + r1.w);
  u16x8 ev;
#pragma unroll
  for (int h = 0; h < 8; ++h) ev[h] = f2b(v[h]);
  *(u16x8*)&ebuf[(size_t)e * 8] = ev;
#pragma unroll
  for (int h = 0; h < 8; ++h) atomicMax(&mxu[d * 8 + h], enc_f(v[h]));
}

// ---- edge pass 2: ex = exp(e - m[dst]) (bf16); segment sum of rounded ex ----
__global__ void k_edge_exp(const int* __restrict__ dst, const unsigned* __restrict__ mxu,
                           unsigned short* __restrict__ ebuf, float* __restrict__ den) {
  int e = blockIdx.x * blockDim.x + threadIdx.x;
  if (e >= E_EDGES) return;
  int d = dst[e];
  u16x8 ev = *(const u16x8*)&ebuf[(size_t)e * 8];
  float exr[8];
#pragma unroll
  for (int h = 0; h < 8; ++h) {
    float ex = expf(b2f(ev[h]) - dec_f(mxu[d * 8 + h]));
    ev[h] = f2b(ex);
    exr[h] = b2f(ev[h]);  // accumulate the rounded value so den matches gather
  }
  *(u16x8*)&ebuf[(size_t)e * 8] = ev;
#pragma unroll
  for (int h = 0; h < 8; ++h) atomicAdd(&den[d * 8 + h], exr[h]);
}

// ---- exclusive prefix sum deg[N] -> rowptr[N+1], shfl-based, single block ----
__global__ __launch_bounds__(1024) void k_scan(const int* __restrict__ deg,
                                               int* __restrict__ rowptr) {
  __shared__ int wsum[16];
  __shared__ int carry;
  const int tid = threadIdx.x, wv = tid >> 6, lane = tid & 63;
  if (tid == 0) carry = 0;
  __syncthreads();
  for (int base = 0; base < N_NODES; base += 1024) {
    int i = base + tid;
    int v = (i < N_NODES) ? deg[i] : 0;
    int x = v;
#pragma unroll
    for (int off = 1; off < 64; off <<= 1) {
      int t = __shfl_up(x, off);
      if (lane >= off) x += t;
    }
    if (lane == 63) wsum[wv] = x;
    __syncthreads();
    if (tid < 16) {
      int y = wsum[tid];
#pragma unroll
      for (int off = 1; off < 16; off <<= 1) {
        int t = __shfl_up(y, off, 16);
        if (tid >= off) y += t;
      }
      wsum[tid] = y;
    }
    __syncthreads();
    int pre = (wv > 0) ? wsum[wv - 1] : 0;
    int incl = carry + pre + x;
    if (i < N_NODES) rowptr[i] = incl - v;
    int tot = wsum[15];
    __syncthreads();
    if (tid == 0) carry += tot;
  }
  if (tid == 0) rowptr[N_NODES] = carry;
}

// ---- scatter edge ids into CSR slots ----
__global__ void k_scatter(const int* __restrict__ dst, const int* __restrict__ rowptr,
                          int* __restrict__ cur, int* __restrict__ csr) {
  int e = blockIdx.x * blockDim.x + threadIdx.x;
  if (e >= E_EDGES) return;
  int d = dst[e];
  int p = atomicAdd(&cur[d], 1);
  csr[rowptr[d] + p] = e;
}

// ---- gather/aggregate: one wave per node; z[n] = elu(agg/den + bg) (bf16) ----
__global__ __launch_bounds__(256) void k_agg(const unsigned short* __restrict__ featb,
                                             const unsigned short* __restrict__ ebuf,
                                             const int* __restrict__ csr,
                                             const int* __restrict__ rowptr,
                                             const int* __restrict__ srcm,
                                             const float* __restrict__ den,
                                             const float* __restrict__ bg,
                                             unsigned short* __restrict__ z) {
  const int lane = threadIdx.x & 63;
  const int n = blockIdx.x * 4 + (threadIdx.x >> 6);
  const int h = lane >> 3;
  float acc[8] = {};
  const int r0 = rowptr[n], r1 = rowptr[n + 1];
  for (int base = r0; base < r1; base += 64) {
    int idx = base + lane;
    int eid = 0, s = 0;
    if (idx < r1) { eid = csr[idx]; s = srcm[eid]; }
    int cnt = min(64, r1 - base);
    int i = 0;
    for (; i + 2 <= cnt; i += 2) {
      int e0 = __shfl(eid, i), s0 = __shfl(s, i);
      int e1 = __shfl(eid, i + 1), s1 = __shfl(s, i + 1);
      float w0 = b2f(ebuf[(size_t)e0 * 8 + h]);
      float w1 = b2f(ebuf[(size_t)e1 * 8 + h]);
      u16x8 f0 = *(const u16x8*)&featb[(size_t)s0 * HD + lane * 8];
      u16x8 f1 = *(const u16x8*)&featb[(size_t)s1 * HD + lane * 8];
#pragma unroll
      for (int j = 0; j < 8; ++j) acc[j] += w0 * b2f(f0[j]);
#pragma unroll
      for (int j = 0; j < 8; ++j) acc[j] += w1 * b2f(f1[j]);
    }
    if (i < cnt) {
      int e0 = __shfl(eid, i), s0 = __shfl(s, i);
      float w0 = b2f(ebuf[(size_t)e0 * 8 + h]);
      u16x8 f0 = *(const u16x8*)&featb[(size_t)s0 * HD + lane * 8];
#pragma unroll
      for (int j = 0; j < 8; ++j) acc[j] += w0 * b2f(f0[j]);
    }
  }
  float ds = 1.f / fmaxf(den[n * 8 + h], 1e-9f);
  u16x8 zo;
#pragma unroll
  for (int j = 0; j < 8; ++j) zo[j] = f2b(eluf(acc[j] * ds + bg[lane * 8 + j]));
  *(u16x8*)&z[(size_t)n * HD + lane * 8] = zo;
}

// ---- GEMM 2: hidden = z @ W1 (bf16 MFMA), fused tanh*q row-sum -> wsem[m] ----
__global__ __launch_bounds__(256) void k_gemm_sem(const unsigned short* __restrict__ Zb,
                                                  const unsigned short* __restrict__ W1T,
                                                  const float* __restrict__ b1,
                                                  const float* __restrict__ qv,
                                                  float* __restrict__ wsem_m) {
  __shared__ __align__(16) unsigned short As[64][72];
  __shared__ __align__(16) unsigned short Bs[64][72];
  const int tid = threadIdx.x;
  const int r0 = blockIdx.x * 64, c0 = blockIdx.y * 64;
  const int w = tid >> 6, lane = tid & 63;
  const int cl = lane & 15, kg = lane >> 4;
  f32x4 acc[4] = {};
  for (int k0 = 0; k0 < HD; k0 += 64) {
#pragma unroll
    for (int p = 0; p < 2; ++p) {
      int c = tid + p * 256;
      int row = c >> 3, ko = (c & 7) * 8;
      u16x8 v;
      if (r0 + row < N_NODES)
        v = *(const u16x8*)&Zb[(size_t)(r0 + row) * HD + k0 + ko];
      else
        v = (u16x8)(unsigned short)0;
      *(u16x8*)&As[row][ko] = v;
      *(u16x8*)&Bs[row][ko] = *(const u16x8*)&W1T[(size_t)(c0 + row) * HD + k0 + ko];
    }
    __syncthreads();
#pragma unroll
    for (int kk = 0; kk < 64; kk += 32) {
      bf16x8 a = *(const bf16x8*)&As[w * 16 + cl][kk + kg * 8];
#pragma unroll
      for (int ct = 0; ct < 4; ++ct) {
        bf16x8 b = *(const bf16x8*)&Bs[ct * 16 + cl][kk + kg * 8];
        acc[ct] = __builtin_amdgcn_mfma_f32_16x16x32_bf16(a, b, acc[ct], 0, 0, 0);
      }
    }
    __syncthreads();
  }
  float rs[4] = {0.f, 0.f, 0.f, 0.f};
#pragma unroll
  for (int ct = 0; ct < 4; ++ct) {
    int col = c0 + ct * 16 + cl;
    float bb = b1[col], qq = qv[col];
#pragma unroll
    for (int reg = 0; reg < 4; ++reg) rs[reg] += tanhf(acc[ct][reg] + bb) * qq;
  }
#pragma unroll
  for (int off = 1; off < 16; off <<= 1) {
#pragma unroll
    for (int reg = 0; reg < 4; ++reg) rs[reg] += __shfl_xor(rs[reg], off);
  }
  float val = 0.f;
#pragma unroll
  for (int reg = 0; reg < 4; ++reg) {
    int row = r0 + w * 16 + kg * 4 + reg;
    if (row < N_NODES) val += rs[reg];
  }
  if (cl == 0) atomicAdd(wsem_m, val);
}

// ---- GEMM 3: y[N,64](fp32) = z @ Wout (bf16 MFMA) ----
__global__ __launch_bounds__(256) void k_gemm_y(const unsigned short* __restrict__ Zb,
                                                const unsigned short* __restrict__ WoT,
                                                float* __restrict__ y) {
  __shared__ __align__(16) unsigned short As[64][72];
  __shared__ __align__(16) unsigned short Bs[64][72];
  const int tid = threadIdx.x;
  const int r0 = blockIdx.x * 64;
  const int w = tid >> 6, lane = tid & 63;
  const int cl = lane & 15, kg = lane >> 4;
  f32x4 acc[4] = {};
  for (int k0 = 0; k0 < HD; k0 += 64) {
#pragma unroll
    for (int p = 0; p < 2; ++p) {
      int c = tid + p * 256;
      int row = c >> 3, ko = (c & 7) * 8;
      u16x8 v;
      if (r0 + row < N_NODES)
        v = *(const u16x8*)&Zb[(size_t)(r0 + row) * HD + k0 + ko];
      else
        v = (u16x8)(unsigned short)0;
      *(u16x8*)&As[row][ko] = v;
      *(u16x8*)&Bs[row][ko] = *(const u16x8*)&WoT[(size_t)row * HD + k0 + ko];
    }
    __syncthreads();
#pragma unroll
    for (int kk = 0; kk < 64; kk += 32) {
      bf16x8 a = *(const bf16x8*)&As[w * 16 + cl][kk + kg * 8];
#pragma unroll
      for (int ct = 0; ct < 4; ++ct) {
        bf16x8 b = *(const bf16x8*)&Bs[ct * 16 + cl][kk + kg * 8];
        acc[ct] = __builtin_amdgcn_mfma_f32_16x16x32_bf16(a, b, acc[ct], 0, 0, 0);
      }
    }
    __syncthreads();
  }
#pragma unroll
  for (int ct = 0; ct < 4; ++ct)
#pragma unroll
    for (int reg = 0; reg < 4; ++reg) {
      int row = r0 + w * 16 + kg * 4 + reg;
      if (row < N_NODES) y[(size_t)row * OUT_DIM + ct * 16 + cl] = acc[ct][reg];
    }
}

// ---- beta = softmax(wsem / N) ----
__global__ void k_beta(const float* __restrict__ wsem, float* __restrict__ beta) {
  float w0 = wsem[0] / (float)N_NODES, w1 = wsem[1] / (float)N_NODES;
  float mx = fmaxf(w0, w1);
  float e0 = expf(w0 - mx), e1 = expf(w1 - mx);
  float inv = 1.f / (e0 + e1);
  beta[0] = e0 * inv;
  beta[1] = e1 * inv;
}

// ---- final: out = beta0*y0 + beta1*y1 + bout ----
__global__ void k_final(const float* __restrict__ y, const float* __restrict__ beta,
                        const float* __restrict__ bout, float* __restrict__ out) {
  int i = blockIdx.x * blockDim.x + threadIdx.x;
  if (i >= N_NODES * OUT_DIM) return;
  float b0 = beta[0], b1 = beta[1];
  out[i] = b0 * y[i] + b1 * y[(size_t)N_NODES * OUT_DIM + i] + bout[i & 63];
}

extern "C" void kernel_launch(void* const* d_in, const int* in_sizes, int n_in,
                              void* d_out, int out_size, void* d_ws, size_t ws_size,
                              hipStream_t stream) {
  const float* x    = (const float*)d_in[0];
  const int*   src  = (const int*)d_in[1];
  const int*   dst  = (const int*)d_in[2];
  const float* Wg   = (const float*)d_in[3];
  const float* al   = (const float*)d_in[4];
  const float* ar   = (const float*)d_in[5];
  const float* bg   = (const float*)d_in[6];
  const float* W1   = (const float*)d_in[7];
  const float* b1   = (const float*)d_in[8];
  const float* q    = (const float*)d_in[9];
  const float* Wout = (const float*)d_in[10];
  const float* bout = (const float*)d_in[11];
  float* out = (float*)d_out;

  // workspace layout (byte offsets, all 16B-aligned); total ~151.8 MB
  char* ws = (char*)d_ws;
  unsigned short* featb = (unsigned short*)(ws);                    // 51,200,000
  unsigned short* z     = (unsigned short*)(ws + 51200000);         // 51,200,000
  unsigned short* ebuf  = (unsigned short*)(ws + 102400000);        // 12,800,000
  float* el             = (float*)(ws + 115200000);                 //  1,600,000
  float* er             = (float*)(ws + 116800000);                 //  1,600,000
  float* den            = (float*)(ws + 118400000);                 //  1,600,000
  unsigned* mxu         = (unsigned*)(ws + 120000000);              //  1,600,000
  int* deg              = (int*)(ws + 121600000);                   //    200,704
  int* cur              = (int*)(ws + 121800704);                   //    200,704
  int* rowptr           = (int*)(ws + 122001408);                   //    200,704
  int* csr              = (int*)(ws + 122202112);                   //  3,200,000
  float* y              = (float*)(ws + 125402112);                 // 25,600,000
  unsigned short* WgbT  = (unsigned short*)(ws + 151002112);        //    524,288
  unsigned short* W1T   = (unsigned short*)(ws + 151526400);        //    131,072
  unsigned short* WoutT = (unsigned short*)(ws + 151657472);        //     65,536
  float* wsem           = (float*)(ws + 151723008);                 //         64
  float* beta           = (float*)(ws + 151723072);                 //         64

  hipMemsetAsync(wsem, 0, 2 * sizeof(float), stream);
  k_prep<<<1408, 256, 0, stream>>>(Wg, W1, Wout, WgbT, W1T, WoutT);

  for (int m = 0; m < M_PATHS; ++m) {
    const int* srcm = src + (size_t)m * E_EDGES;
    const int* dstm = dst + (size_t)m * E_EDGES;
    k_init<<<1563, 256, 0, stream>>>(mxu, den, deg, cur);
    dim3 gf(782, 8);
    k_gemm_feat<<<gf, 256, 0, stream>>>(x, WgbT + (size_t)m * 131072, featb);
    k_elr<<<1563, 256, 0, stream>>>(featb, al + m * HD, ar + m * HD, el, er);
    k_edge_max<<<3125, 256, 0, stream>>>(srcm, dstm, el, er, ebuf, mxu, deg);
    k_edge_exp<<<3125, 256, 0, stream>>>(dstm, mxu, ebuf, den);
    k_scan<<<1, 1024, 0, stream>>>(deg, rowptr);
    k_scatter<<<3125, 256, 0, stream>>>(dstm, rowptr, cur, csr);
    k_agg<<<12500, 256, 0, stream>>>(featb, ebuf, csr, rowptr, srcm, den,
                                     bg + m * HD, z);
    dim3 gs(782, 2);
    k_gemm_sem<<<gs, 256, 0, stream>>>(z, W1T, b1, q, wsem + m);
    k_gemm_y<<<782, 256, 0, stream>>>(z, WoutT, y + (size_t)m * N_NODES * OUT_DIM);
  }
  k_beta<<<1, 1, 0, stream>>>(wsem, beta);
  k_final<<<12500, 256, 0, stream>>>(y, beta, bout, out);
}

// Round 3
// 1010.866 us; speedup vs baseline: 3.5164x; 2.1379x over previous
//
#include <hip/hip_runtime.h>
#include <cstdint>

#define N_NODES 50000
#define IN_DIM 256
#define H_HEADS 8
#define D_HEAD 64
#define HD 512
#define OUT_DIM 64
#define M_PATHS 2
#define E_EDGES 800000
#define SEM_HID 128
#define NEG_SLOPE 0.2f

typedef __attribute__((ext_vector_type(8))) short bf16x8;
typedef __attribute__((ext_vector_type(4))) float f32x4;
typedef __attribute__((ext_vector_type(8))) unsigned short u16x8;

// ---- bf16 helpers ----
__device__ __forceinline__ float b2f(unsigned short u) {
  return __uint_as_float(((unsigned)u) << 16);
}
__device__ __forceinline__ unsigned short f2b(float f) {
  unsigned u = __float_as_uint(f);
  unsigned r = (u + 0x7fffu + ((u >> 16) & 1u)) >> 16;
  return (unsigned short)r;
}

__device__ __forceinline__ float eluf(float x) {
  return x > 0.f ? x : (expf(x) - 1.f);
}
__device__ __forceinline__ float lrelu(float x) {
  return x > 0.f ? x : NEG_SLOPE * x;
}

// ---- weight conversion + transpose to bf16 [col][k] layouts ----
__global__ void k_prep(const float* __restrict__ Wg, const float* __restrict__ W1,
                       const float* __restrict__ Wout, unsigned short* __restrict__ WgbT,
                       unsigned short* __restrict__ W1T, unsigned short* __restrict__ WoutT) {
  int gid = blockIdx.x * blockDim.x + threadIdx.x;
  if (gid < 262144) {
    int m = gid >> 17, r = gid & 131071, n = r >> 8, k = r & 255;
    WgbT[(size_t)m * 131072 + n * 256 + k] = f2b(Wg[(size_t)m * 131072 + k * 512 + n]);
  } else if (gid < 327680) {
    int r = gid - 262144; int c = r >> 9, k = r & 511;
    W1T[c * 512 + k] = f2b(W1[k * 128 + c]);
  } else if (gid < 360448) {
    int r = gid - 327680; int c = r >> 9, k = r & 511;
    WoutT[c * 512 + k] = f2b(Wout[k * 64 + c]);
  }
}

// ---- GEMM 1: featb[N,512](bf16) = x[N,256](fp32, converted) @ Wg ----
__global__ __launch_bounds__(256) void k_gemm_feat(const float* __restrict__ A,
                                                   const unsigned short* __restrict__ BT,
                                                   unsigned short* __restrict__ C) {
  __shared__ __align__(16) unsigned short As[64][72];
  __shared__ __align__(16) unsigned short Bs[64][72];
  const int tid = threadIdx.x;
  const int r0 = blockIdx.x * 64, c0 = blockIdx.y * 64;
  const int w = tid >> 6, lane = tid & 63;
  const int cl = lane & 15, kg = lane >> 4;
  f32x4 acc[4] = {};
  for (int k0 = 0; k0 < IN_DIM; k0 += 64) {
#pragma unroll
    for (int p = 0; p < 2; ++p) {
      int c = tid + p * 256;
      int row = c >> 3, ko = (c & 7) * 8;
      u16x8 v;
      if (r0 + row < N_NODES) {
        const float4* g = (const float4*)&A[(size_t)(r0 + row) * IN_DIM + k0 + ko];
        float4 g0 = g[0], g1 = g[1];
        v[0] = f2b(g0.x); v[1] = f2b(g0.y); v[2] = f2b(g0.z); v[3] = f2b(g0.w);
        v[4] = f2b(g1.x); v[5] = f2b(g1.y); v[6] = f2b(g1.z); v[7] = f2b(g1.w);
      } else {
        v = (u16x8)(unsigned short)0;
      }
      *(u16x8*)&As[row][ko] = v;
      *(u16x8*)&Bs[row][ko] = *(const u16x8*)&BT[(size_t)(c0 + row) * IN_DIM + k0 + ko];
    }
    __syncthreads();
#pragma unroll
    for (int kk = 0; kk < 64; kk += 32) {
      bf16x8 a = *(const bf16x8*)&As[w * 16 + cl][kk + kg * 8];
#pragma unroll
      for (int ct = 0; ct < 4; ++ct) {
        bf16x8 b = *(const bf16x8*)&Bs[ct * 16 + cl][kk + kg * 8];
        acc[ct] = __builtin_amdgcn_mfma_f32_16x16x32_bf16(a, b, acc[ct], 0, 0, 0);
      }
    }
    __syncthreads();
  }
#pragma unroll
  for (int ct = 0; ct < 4; ++ct)
#pragma unroll
    for (int reg = 0; reg < 4; ++reg) {
      int row = r0 + w * 16 + kg * 4 + reg;
      if (row < N_NODES) C[(size_t)row * HD + c0 + ct * 16 + cl] = f2b(acc[ct][reg]);
    }
}

// ---- el/er per (node, head) from bf16 feat ----
__global__ void k_elr(const unsigned short* __restrict__ featb, const float* __restrict__ al,
                      const float* __restrict__ ar, float* __restrict__ el,
                      float* __restrict__ er) {
  int gid = blockIdx.x * blockDim.x + threadIdx.x;
  if (gid >= N_NODES * H_HEADS) return;
  int n = gid >> 3, h = gid & 7;
  const u16x8* f8 = (const u16x8*)&featb[(size_t)n * HD + h * D_HEAD];
  float sl = 0.f, sr = 0.f;
#pragma unroll
  for (int c = 0; c < 8; ++c) {
    u16x8 f = f8[c];
#pragma unroll
    for (int j = 0; j < 8; ++j) {
      float v = b2f(f[j]);
      sl += v * al[h * D_HEAD + c * 8 + j];
      sr += v * ar[h * D_HEAD + c * 8 + j];
    }
  }
  el[gid] = sl;
  er[gid] = sr;
}

// ---- edge pass: e = leaky(el[src]+er[dst]) -> bf16 ebuf; degree count ----
__global__ void k_edge_e(const int* __restrict__ src, const int* __restrict__ dst,
                         const float* __restrict__ el, const float* __restrict__ er,
                         unsigned short* __restrict__ ebuf, int* __restrict__ deg) {
  int e = blockIdx.x * blockDim.x + threadIdx.x;
  if (e >= E_EDGES) return;
  int s = src[e], d = dst[e];
  atomicAdd(&deg[d], 1);
  float4 l0 = *(const float4*)&el[s * 8], l1 = *(const float4*)&el[s * 8 + 4];
  float4 r0 = *(const float4*)&er[d * 8], r1 = *(const float4*)&er[d * 8 + 4];
  u16x8 ev;
  ev[0] = f2b(lrelu(l0.x + r0.x)); ev[1] = f2b(lrelu(l0.y + r0.y));
  ev[2] = f2b(lrelu(l0.z + r0.z)); ev[3] = f2b(lrelu(l0.w + r0.w));
  ev[4] = f2b(lrelu(l1.x + r1.x)); ev[5] = f2b(lrelu(l1.y + r1.y));
  ev[6] = f2b(lrelu(l1.z + r1.z)); ev[7] = f2b(lrelu(l1.w + r1.w));
  *(u16x8*)&ebuf[(size_t)e * 8] = ev;
}

// ---- exclusive prefix sum deg[N] -> rowptr[N+1], shfl-based, single block ----
__global__ __launch_bounds__(1024) void k_scan(const int* __restrict__ deg,
                                               int* __restrict__ rowptr) {
  __shared__ int wsum[16];
  __shared__ int carry;
  const int tid = threadIdx.x, wv = tid >> 6, lane = tid & 63;
  if (tid == 0) carry = 0;
  __syncthreads();
  for (int base = 0; base < N_NODES; base += 1024) {
    int i = base + tid;
    int v = (i < N_NODES) ? deg[i] : 0;
    int x = v;
#pragma unroll
    for (int off = 1; off < 64; off <<= 1) {
      int t = __shfl_up(x, off);
      if (lane >= off) x += t;
    }
    if (lane == 63) wsum[wv] = x;
    __syncthreads();
    if (tid < 16) {
      int y = wsum[tid];
#pragma unroll
      for (int off = 1; off < 16; off <<= 1) {
        int t = __shfl_up(y, off, 16);
        if (tid >= off) y += t;
      }
      wsum[tid] = y;
    }
    __syncthreads();
    int pre = (wv > 0) ? wsum[wv - 1] : 0;
    int incl = carry + pre + x;
    if (i < N_NODES) rowptr[i] = incl - v;
    int tot = wsum[15];
    __syncthreads();
    if (tid == 0) carry += tot;
  }
  if (tid == 0) rowptr[N_NODES] = carry;
}

// ---- scatter edge ids into CSR slots ----
__global__ void k_scatter(const int* __restrict__ dst, const int* __restrict__ rowptr,
                          int* __restrict__ cur, int* __restrict__ csr) {
  int e = blockIdx.x * blockDim.x + threadIdx.x;
  if (e >= E_EDGES) return;
  int d = dst[e];
  int p = atomicAdd(&cur[d], 1);
  csr[rowptr[d] + p] = e;
}

// ---- gather/aggregate: one wave per node; softmax max+den computed in-wave ----
__global__ __launch_bounds__(256) void k_agg(const unsigned short* __restrict__ featb,
                                             const unsigned short* __restrict__ ebuf,
                                             const int* __restrict__ csr,
                                             const int* __restrict__ rowptr,
                                             const int* __restrict__ srcm,
                                             const float* __restrict__ bg,
                                             unsigned short* __restrict__ z) {
  const int lane = threadIdx.x & 63;
  const int n = blockIdx.x * 4 + (threadIdx.x >> 6);
  const int h = lane >> 3;
  const int r0 = rowptr[n], r1 = rowptr[n + 1];
  // phase A: per-head max over this node's incoming edge scores
  float mx[8];
#pragma unroll
  for (int j = 0; j < 8; ++j) mx[j] = -1e30f;
  for (int idx = r0 + lane; idx < r1; idx += 64) {
    int eid = csr[idx];
    u16x8 ev = *(const u16x8*)&ebuf[(size_t)eid * 8];
#pragma unroll
    for (int j = 0; j < 8; ++j) mx[j] = fmaxf(mx[j], b2f(ev[j]));
  }
#pragma unroll
  for (int off = 1; off < 64; off <<= 1)
#pragma unroll
    for (int j = 0; j < 8; ++j) mx[j] = fmaxf(mx[j], __shfl_xor(mx[j], off));
  const float mh = mx[h];
  // phase B: weighted aggregate + in-register denominator
  float acc[8] = {};
  float densum = 0.f;
  for (int base = r0; base < r1; base += 64) {
    int idx = base + lane;
    int eid = 0, s = 0;
    if (idx < r1) { eid = csr[idx]; s = srcm[eid]; }
    int cnt = min(64, r1 - base);
    int i = 0;
    for (; i + 2 <= cnt; i += 2) {
      int e0 = __shfl(eid, i), s0 = __shfl(s, i);
      int e1 = __shfl(eid, i + 1), s1 = __shfl(s, i + 1);
      float w0 = expf(b2f(ebuf[(size_t)e0 * 8 + h]) - mh);
      float w1 = expf(b2f(ebuf[(size_t)e1 * 8 + h]) - mh);
      densum += w0 + w1;
      u16x8 f0 = *(const u16x8*)&featb[(size_t)s0 * HD + lane * 8];
      u16x8 f1 = *(const u16x8*)&featb[(size_t)s1 * HD + lane * 8];
#pragma unroll
      for (int j = 0; j < 8; ++j) acc[j] += w0 * b2f(f0[j]);
#pragma unroll
      for (int j = 0; j < 8; ++j) acc[j] += w1 * b2f(f1[j]);
    }
    if (i < cnt) {
      int e0 = __shfl(eid, i), s0 = __shfl(s, i);
      float w0 = expf(b2f(ebuf[(size_t)e0 * 8 + h]) - mh);
      densum += w0;
      u16x8 f0 = *(const u16x8*)&featb[(size_t)s0 * HD + lane * 8];
#pragma unroll
      for (int j = 0; j < 8; ++j) acc[j] += w0 * b2f(f0[j]);
    }
  }
  float ds = 1.f / fmaxf(densum, 1e-9f);
  u16x8 zo;
#pragma unroll
  for (int j = 0; j < 8; ++j) zo[j] = f2b(eluf(acc[j] * ds + bg[lane * 8 + j]));
  *(u16x8*)&z[(size_t)n * HD + lane * 8] = zo;
}

// ---- GEMM 2: hidden = z @ W1 (bf16 MFMA), fused tanh*q row-sum -> wsem[m] ----
__global__ __launch_bounds__(256) void k_gemm_sem(const unsigned short* __restrict__ Zb,
                                                  const unsigned short* __restrict__ W1T,
                                                  const float* __restrict__ b1,
                                                  const float* __restrict__ qv,
                                                  float* __restrict__ wsem_m) {
  __shared__ __align__(16) unsigned short As[64][72];
  __shared__ __align__(16) unsigned short Bs[64][72];
  const int tid = threadIdx.x;
  const int r0 = blockIdx.x * 64, c0 = blockIdx.y * 64;
  const int w = tid >> 6, lane = tid & 63;
  const int cl = lane & 15, kg = lane >> 4;
  f32x4 acc[4] = {};
  for (int k0 = 0; k0 < HD; k0 += 64) {
#pragma unroll
    for (int p = 0; p < 2; ++p) {
      int c = tid + p * 256;
      int row = c >> 3, ko = (c & 7) * 8;
      u16x8 v;
      if (r0 + row < N_NODES)
        v = *(const u16x8*)&Zb[(size_t)(r0 + row) * HD + k0 + ko];
      else
        v = (u16x8)(unsigned short)0;
      *(u16x8*)&As[row][ko] = v;
      *(u16x8*)&Bs[row][ko] = *(const u16x8*)&W1T[(size_t)(c0 + row) * HD + k0 + ko];
    }
    __syncthreads();
#pragma unroll
    for (int kk = 0; kk < 64; kk += 32) {
      bf16x8 a = *(const bf16x8*)&As[w * 16 + cl][kk + kg * 8];
#pragma unroll
      for (int ct = 0; ct < 4; ++ct) {
        bf16x8 b = *(const bf16x8*)&Bs[ct * 16 + cl][kk + kg * 8];
        acc[ct] = __builtin_amdgcn_mfma_f32_16x16x32_bf16(a, b, acc[ct], 0, 0, 0);
      }
    }
    __syncthreads();
  }
  float rs[4] = {0.f, 0.f, 0.f, 0.f};
#pragma unroll
  for (int ct = 0; ct < 4; ++ct) {
    int col = c0 + ct * 16 + cl;
    float bb = b1[col], qq = qv[col];
#pragma unroll
    for (int reg = 0; reg < 4; ++reg) rs[reg] += tanhf(acc[ct][reg] + bb) * qq;
  }
#pragma unroll
  for (int off = 1; off < 16; off <<= 1) {
#pragma unroll
    for (int reg = 0; reg < 4; ++reg) rs[reg] += __shfl_xor(rs[reg], off);
  }
  float val = 0.f;
#pragma unroll
  for (int reg = 0; reg < 4; ++reg) {
    int row = r0 + w * 16 + kg * 4 + reg;
    if (row < N_NODES) val += rs[reg];
  }
  if (cl == 0) atomicAdd(wsem_m, val);
}

// ---- GEMM 3: y[N,64](fp32) = z @ Wout (bf16 MFMA) ----
__global__ __launch_bounds__(256) void k_gemm_y(const unsigned short* __restrict__ Zb,
                                                const unsigned short* __restrict__ WoT,
                                                float* __restrict__ y) {
  __shared__ __align__(16) unsigned short As[64][72];
  __shared__ __align__(16) unsigned short Bs[64][72];
  const int tid = threadIdx.x;
  const int r0 = blockIdx.x * 64;
  const int w = tid >> 6, lane = tid & 63;
  const int cl = lane & 15, kg = lane >> 4;
  f32x4 acc[4] = {};
  for (int k0 = 0; k0 < HD; k0 += 64) {
#pragma unroll
    for (int p = 0; p < 2; ++p) {
      int c = tid + p * 256;
      int row = c >> 3, ko = (c & 7) * 8;
      u16x8 v;
      if (r0 + row < N_NODES)
        v = *(const u16x8*)&Zb[(size_t)(r0 + row) * HD + k0 + ko];
      else
        v = (u16x8)(unsigned short)0;
      *(u16x8*)&As[row][ko] = v;
      *(u16x8*)&Bs[row][ko] = *(const u16x8*)&WoT[(size_t)row * HD + k0 + ko];
    }
    __syncthreads();
#pragma unroll
    for (int kk = 0; kk < 64; kk += 32) {
      bf16x8 a = *(const bf16x8*)&As[w * 16 + cl][kk + kg * 8];
#pragma unroll
      for (int ct = 0; ct < 4; ++ct) {
        bf16x8 b = *(const bf16x8*)&Bs[ct * 16 + cl][kk + kg * 8];
        acc[ct] = __builtin_amdgcn_mfma_f32_16x16x32_bf16(a, b, acc[ct], 0, 0, 0);
      }
    }
    __syncthreads();
  }
#pragma unroll
  for (int ct = 0; ct < 4; ++ct)
#pragma unroll
    for (int reg = 0; reg < 4; ++reg) {
      int row = r0 + w * 16 + kg * 4 + reg;
      if (row < N_NODES) y[(size_t)row * OUT_DIM + ct * 16 + cl] = acc[ct][reg];
    }
}

// ---- beta = softmax(wsem / N) ----
__global__ void k_beta(const float* __restrict__ wsem, float* __restrict__ beta) {
  float w0 = wsem[0] / (float)N_NODES, w1 = wsem[1] / (float)N_NODES;
  float mx = fmaxf(w0, w1);
  float e0 = expf(w0 - mx), e1 = expf(w1 - mx);
  float inv = 1.f / (e0 + e1);
  beta[0] = e0 * inv;
  beta[1] = e1 * inv;
}

// ---- final: out = beta0*y0 + beta1*y1 + bout ----
__global__ void k_final(const float* __restrict__ y, const float* __restrict__ beta,
                        const float* __restrict__ bout, float* __restrict__ out) {
  int i = blockIdx.x * blockDim.x + threadIdx.x;
  if (i >= N_NODES * OUT_DIM) return;
  float b0 = beta[0], b1 = beta[1];
  out[i] = b0 * y[i] + b1 * y[(size_t)N_NODES * OUT_DIM + i] + bout[i & 63];
}

extern "C" void kernel_launch(void* const* d_in, const int* in_sizes, int n_in,
                              void* d_out, int out_size, void* d_ws, size_t ws_size,
                              hipStream_t stream) {
  const float* x    = (const float*)d_in[0];
  const int*   src  = (const int*)d_in[1];
  const int*   dst  = (const int*)d_in[2];
  const float* Wg   = (const float*)d_in[3];
  const float* al   = (const float*)d_in[4];
  const float* ar   = (const float*)d_in[5];
  const float* bg   = (const float*)d_in[6];
  const float* W1   = (const float*)d_in[7];
  const float* b1   = (const float*)d_in[8];
  const float* q    = (const float*)d_in[9];
  const float* Wout = (const float*)d_in[10];
  const float* bout = (const float*)d_in[11];
  float* out = (float*)d_out;

  // workspace layout (byte offsets, all 16B-aligned); total ~148.5 MB
  char* ws = (char*)d_ws;
  unsigned short* featb = (unsigned short*)(ws);                    // 51,200,000
  unsigned short* z     = (unsigned short*)(ws + 51200000);         // 51,200,000
  unsigned short* ebuf  = (unsigned short*)(ws + 102400000);        // 12,800,000
  float* el             = (float*)(ws + 115200000);                 //  1,600,000
  float* er             = (float*)(ws + 116800000);                 //  1,600,000
  int* deg              = (int*)(ws + 118400000);                   //    200,704
  int* cur              = (int*)(ws + 118600704);                   //    200,704
  int* rowptr           = (int*)(ws + 118801408);                   //    200,704
  int* csr              = (int*)(ws + 119002112);                   //  3,200,000
  float* y              = (float*)(ws + 122202112);                 // 25,600,000
  unsigned short* WgbT  = (unsigned short*)(ws + 147802112);        //    524,288
  unsigned short* W1T   = (unsigned short*)(ws + 148326400);        //    131,072
  unsigned short* WoutT = (unsigned short*)(ws + 148457472);        //     65,536
  float* wsem           = (float*)(ws + 148523008);                 //         64
  float* beta           = (float*)(ws + 148523072);                 //         64

  hipMemsetAsync(wsem, 0, 2 * sizeof(float), stream);
  k_prep<<<1408, 256, 0, stream>>>(Wg, W1, Wout, WgbT, W1T, WoutT);

  for (int m = 0; m < M_PATHS; ++m) {
    const int* srcm = src + (size_t)m * E_EDGES;
    const int* dstm = dst + (size_t)m * E_EDGES;
    dim3 gf(782, 8);
    k_gemm_feat<<<gf, 256, 0, stream>>>(x, WgbT + (size_t)m * 131072, featb);
    k_elr<<<1563, 256, 0, stream>>>(featb, al + m * HD, ar + m * HD, el, er);
    hipMemsetAsync(deg, 0, 2 * 200704, stream);  // deg + cur
    k_edge_e<<<3125, 256, 0, stream>>>(srcm, dstm, el, er, ebuf, deg);
    k_scan<<<1, 1024, 0, stream>>>(deg, rowptr);
    k_scatter<<<3125, 256, 0, stream>>>(dstm, rowptr, cur, csr);
    k_agg<<<12500, 256, 0, stream>>>(featb, ebuf, csr, rowptr, srcm,
                                     bg + m * HD, z);
    dim3 gs(782, 2);
    k_gemm_sem<<<gs, 256, 0, stream>>>(z, W1T, b1, q, wsem + m);
    k_gemm_y<<<782, 256, 0, stream>>>(z, WoutT, y + (size_t)m * N_NODES * OUT_DIM);
  }
  k_beta<<<1, 1, 0, stream>>>(wsem, beta);
  k_final<<<12500, 256, 0, stream>>>(y, beta, bout, out);
}

// Round 4
// 562.421 us; speedup vs baseline: 6.3201x; 1.7973x over previous
//
#include <hip/hip_runtime.h>
#include <cstdint>

#define N_NODES 50000
#define IN_DIM 256
#define H_HEADS 8
#define D_HEAD 64
#define HD 512
#define OUT_DIM 64
#define M_PATHS 2
#define E_EDGES 800000
#define SEM_HID 128
#define NEG_SLOPE 0.2f
#define ELL_CAP 64

typedef __attribute__((ext_vector_type(8))) short bf16x8;
typedef __attribute__((ext_vector_type(4))) float f32x4;
typedef __attribute__((ext_vector_type(8))) unsigned short u16x8;

// ---- bf16 helpers ----
__device__ __forceinline__ float b2f(unsigned short u) {
  return __uint_as_float(((unsigned)u) << 16);
}
__device__ __forceinline__ unsigned short f2b(float f) {
  unsigned u = __float_as_uint(f);
  unsigned r = (u + 0x7fffu + ((u >> 16) & 1u)) >> 16;
  return (unsigned short)r;
}

__device__ __forceinline__ float eluf(float x) {
  return x > 0.f ? x : (expf(x) - 1.f);
}
__device__ __forceinline__ float lrelu(float x) {
  return x > 0.f ? x : NEG_SLOPE * x;
}

// ---- weight conversion + transpose to bf16 [col][k] layouts ----
__global__ void k_prep(const float* __restrict__ Wg, const float* __restrict__ W1,
                       const float* __restrict__ Wout, unsigned short* __restrict__ WgbT,
                       unsigned short* __restrict__ W1T, unsigned short* __restrict__ WoutT) {
  int gid = blockIdx.x * blockDim.x + threadIdx.x;
  if (gid < 262144) {
    int m = gid >> 17, r = gid & 131071, n = r >> 8, k = r & 255;
    WgbT[(size_t)m * 131072 + n * 256 + k] = f2b(Wg[(size_t)m * 131072 + k * 512 + n]);
  } else if (gid < 327680) {
    int r = gid - 262144; int c = r >> 9, k = r & 511;
    W1T[c * 512 + k] = f2b(W1[k * 128 + c]);
  } else if (gid < 360448) {
    int r = gid - 327680; int c = r >> 9, k = r & 511;
    WoutT[c * 512 + k] = f2b(Wout[k * 64 + c]);
  }
}

// ---- edge pass: build ELL adjacency (by dst) ----
__global__ void k_edge_e(const int* __restrict__ src, const int* __restrict__ dst,
                         int* __restrict__ deg, int* __restrict__ ell_src) {
  int e = blockIdx.x * blockDim.x + threadIdx.x;
  if (e >= E_EDGES) return;
  int d = dst[e];
  int p = atomicAdd(&deg[d], 1);
  if (p < ELL_CAP) ell_src[d * ELL_CAP + p] = src[e];
}

// ---- GEMM 1: featb[N,512](bf16) = x[N,256] @ Wg; fused el/er epilogue ----
// 64 rows x 256 cols per block; 4 waves in 2x2 (row-half, col-half) layout.
__global__ __launch_bounds__(256) void k_gemm_feat(const float* __restrict__ xfp,
                                                   const unsigned short* __restrict__ BT,
                                                   const float* __restrict__ al,
                                                   const float* __restrict__ ar,
                                                   unsigned short* __restrict__ C,
                                                   float* __restrict__ el,
                                                   float* __restrict__ er) {
  __shared__ __align__(16) unsigned short As[64][72];
  __shared__ __align__(16) unsigned short Bs[256][72];
  const int tid = threadIdx.x;
  const int r0 = blockIdx.x * 64, c0 = blockIdx.y * 256;
  const int w = tid >> 6, lane = tid & 63;
  const int cl = lane & 15, kg = lane >> 4;
  const int rw = (w >> 1) * 32;      // row-half base (0 or 32)
  const int cw = (w & 1) * 128;      // col-half base (0 or 128)
  f32x4 acc[2][8] = {};
  for (int k0 = 0; k0 < IN_DIM; k0 += 64) {
#pragma unroll
    for (int p = 0; p < 2; ++p) {
      int idx = tid + p * 256;
      int row = idx >> 3, ko = (idx & 7) * 8;
      u16x8 v = (u16x8)(unsigned short)0;
      int grow = r0 + row;
      if (grow < N_NODES) {
        const float4* g = (const float4*)&xfp[(size_t)grow * IN_DIM + k0 + ko];
        float4 g0 = g[0], g1 = g[1];
        v[0] = f2b(g0.x); v[1] = f2b(g0.y); v[2] = f2b(g0.z); v[3] = f2b(g0.w);
        v[4] = f2b(g1.x); v[5] = f2b(g1.y); v[6] = f2b(g1.z); v[7] = f2b(g1.w);
      }
      *(u16x8*)&As[row][ko] = v;
    }
#pragma unroll
    for (int p = 0; p < 8; ++p) {
      int idx = tid + p * 256;
      int col = idx >> 3, ko = (idx & 7) * 8;
      *(u16x8*)&Bs[col][ko] = *(const u16x8*)&BT[(size_t)(c0 + col) * IN_DIM + k0 + ko];
    }
    __syncthreads();
#pragma unroll
    for (int kk = 0; kk < 64; kk += 32) {
      bf16x8 a0 = *(const bf16x8*)&As[rw + cl][kk + kg * 8];
      bf16x8 a1 = *(const bf16x8*)&As[rw + 16 + cl][kk + kg * 8];
#pragma unroll
      for (int ct = 0; ct < 8; ++ct) {
        bf16x8 b = *(const bf16x8*)&Bs[cw + ct * 16 + cl][kk + kg * 8];
        acc[0][ct] = __builtin_amdgcn_mfma_f32_16x16x32_bf16(a0, b, acc[0][ct], 0, 0, 0);
        acc[1][ct] = __builtin_amdgcn_mfma_f32_16x16x32_bf16(a1, b, acc[1][ct], 0, 0, 0);
      }
    }
    __syncthreads();
  }
  const int ccol = c0 + cw;
  // C write (bf16)
#pragma unroll
  for (int rt = 0; rt < 2; ++rt)
#pragma unroll
    for (int ct = 0; ct < 8; ++ct)
#pragma unroll
      for (int reg = 0; reg < 4; ++reg) {
        int row = r0 + rw + rt * 16 + kg * 4 + reg;
        if (row < N_NODES) C[(size_t)row * HD + ccol + ct * 16 + cl] = f2b(acc[rt][ct][reg]);
      }
  // fused el/er: this wave covers 2 heads (128 cols)
  const int hb = ccol >> 6;
#pragma unroll
  for (int g = 0; g < 2; ++g) {
    float elp[2][4] = {};
    float erp[2][4] = {};
#pragma unroll
    for (int cc = 0; cc < 4; ++cc) {
      int ct = g * 4 + cc;
      float av = al[(hb + g) * 64 + cc * 16 + cl];
      float rv = ar[(hb + g) * 64 + cc * 16 + cl];
#pragma unroll
      for (int rt = 0; rt < 2; ++rt)
#pragma unroll
        for (int reg = 0; reg < 4; ++reg) {
          elp[rt][reg] += acc[rt][ct][reg] * av;
          erp[rt][reg] += acc[rt][ct][reg] * rv;
        }
    }
#pragma unroll
    for (int off = 1; off < 16; off <<= 1)
#pragma unroll
      for (int rt = 0; rt < 2; ++rt)
#pragma unroll
        for (int reg = 0; reg < 4; ++reg) {
          elp[rt][reg] += __shfl_xor(elp[rt][reg], off);
          erp[rt][reg] += __shfl_xor(erp[rt][reg], off);
        }
    if (cl == 0) {
#pragma unroll
      for (int rt = 0; rt < 2; ++rt)
#pragma unroll
        for (int reg = 0; reg < 4; ++reg) {
          int row = r0 + rw + rt * 16 + kg * 4 + reg;
          if (row < N_NODES) {
            el[row * 8 + hb + g] = elp[rt][reg];
            er[row * 8 + hb + g] = erp[rt][reg];
          }
        }
    }
  }
}

// ---- gather/aggregate: one wave per node; scores recomputed in-wave ----
__global__ __launch_bounds__(256) void k_agg(const unsigned short* __restrict__ featb,
                                             const float* __restrict__ el,
                                             const float* __restrict__ er,
                                             const int* __restrict__ ell_src,
                                             const int* __restrict__ deg,
                                             const float* __restrict__ bg,
                                             unsigned short* __restrict__ z) {
  __shared__ float lds_ex[4][544];  // 8 heads x stride 68 per wave
  const int tid = threadIdx.x;
  const int widx = tid >> 6, lane = tid & 63;
  const int n = blockIdx.x * 4 + widx;
  const int h = lane >> 3;
  const int dcnt = min(deg[n], ELL_CAP);
  // phase A: lane i owns edge i; compute leaky scores (fp32)
  float evf[8];
#pragma unroll
  for (int j = 0; j < 8; ++j) evf[j] = -1e30f;
  int s_reg = 0;
  if (lane < dcnt) {
    s_reg = ell_src[n * ELL_CAP + lane];
    const float4* e4 = (const float4*)&el[s_reg * 8];
    float4 a0 = e4[0], a1 = e4[1];
    const float4* r4 = (const float4*)&er[n * 8];
    float4 b0 = r4[0], b1v = r4[1];
    evf[0] = lrelu(a0.x + b0.x); evf[1] = lrelu(a0.y + b0.y);
    evf[2] = lrelu(a0.z + b0.z); evf[3] = lrelu(a0.w + b0.w);
    evf[4] = lrelu(a1.x + b1v.x); evf[5] = lrelu(a1.y + b1v.y);
    evf[6] = lrelu(a1.z + b1v.z); evf[7] = lrelu(a1.w + b1v.w);
  }
  // per-head max over edges (butterfly)
  float mx[8];
#pragma unroll
  for (int j = 0; j < 8; ++j) mx[j] = evf[j];
#pragma unroll
  for (int off = 1; off < 64; off <<= 1)
#pragma unroll
    for (int j = 0; j < 8; ++j) mx[j] = fmaxf(mx[j], __shfl_xor(mx[j], off));
  // exp weights -> LDS (conflict-free stride 68)
#pragma unroll
  for (int j = 0; j < 8; ++j) {
    float exv = (lane < dcnt) ? expf(evf[j] - mx[j]) : 0.f;
    lds_ex[widx][j * 68 + lane] = exv;
  }
  // phase B: weighted aggregate, 4 rows in flight
  float acc[8] = {};
  float densum = 0.f;
  const float* exrow = &lds_ex[widx][h * 68];
  const unsigned short* fb = featb + lane * 8;
  int i = 0;
  for (; i + 4 <= dcnt; i += 4) {
    int s0 = __shfl(s_reg, i),     s1 = __shfl(s_reg, i + 1);
    int s2 = __shfl(s_reg, i + 2), s3 = __shfl(s_reg, i + 3);
    float w0 = exrow[i], w1 = exrow[i + 1], w2 = exrow[i + 2], w3 = exrow[i + 3];
    u16x8 f0 = *(const u16x8*)&fb[(size_t)s0 * HD];
    u16x8 f1 = *(const u16x8*)&fb[(size_t)s1 * HD];
    u16x8 f2 = *(const u16x8*)&fb[(size_t)s2 * HD];
    u16x8 f3 = *(const u16x8*)&fb[(size_t)s3 * HD];
    densum += (w0 + w1) + (w2 + w3);
#pragma unroll
    for (int j = 0; j < 8; ++j) acc[j] += w0 * b2f(f0[j]);
#pragma unroll
    for (int j = 0; j < 8; ++j) acc[j] += w1 * b2f(f1[j]);
#pragma unroll
    for (int j = 0; j < 8; ++j) acc[j] += w2 * b2f(f2[j]);
#pragma unroll
    for (int j = 0; j < 8; ++j) acc[j] += w3 * b2f(f3[j]);
  }
  for (; i < dcnt; ++i) {
    int s0 = __shfl(s_reg, i);
    float w0 = exrow[i];
    u16x8 f0 = *(const u16x8*)&fb[(size_t)s0 * HD];
    densum += w0;
#pragma unroll
    for (int j = 0; j < 8; ++j) acc[j] += w0 * b2f(f0[j]);
  }
  float ds = 1.f / fmaxf(densum, 1e-9f);
  const float4* bg4 = (const float4*)&bg[lane * 8];
  float4 bga = bg4[0], bgb = bg4[1];
  float bgv[8] = {bga.x, bga.y, bga.z, bga.w, bgb.x, bgb.y, bgb.z, bgb.w};
  u16x8 zo;
#pragma unroll
  for (int j = 0; j < 8; ++j) zo[j] = f2b(eluf(acc[j] * ds + bgv[j]));
  *(u16x8*)&z[(size_t)n * HD + lane * 8] = zo;
}

// ---- GEMM 2 (fused): [hidden|y] = z @ [W1|Wout]; tanh*q row-sum + y(bf16) ----
__global__ __launch_bounds__(256) void k_gemm_post(const unsigned short* __restrict__ Zb,
                                                   const unsigned short* __restrict__ W1T,
                                                   const unsigned short* __restrict__ WoutT,
                                                   const float* __restrict__ b1,
                                                   const float* __restrict__ qv,
                                                   float* __restrict__ wsem_m,
                                                   unsigned short* __restrict__ yb) {
  __shared__ __align__(16) unsigned short As[64][72];
  __shared__ __align__(16) unsigned short Bs[192][72];
  __shared__ float redv[16];
  const int tid = threadIdx.x;
  const int r0 = blockIdx.x * 64;
  const int w = tid >> 6, lane = tid & 63;
  const int cl = lane & 15, kg = lane >> 4;
  f32x4 acc[12] = {};
  for (int k0 = 0; k0 < HD; k0 += 64) {
#pragma unroll
    for (int p = 0; p < 2; ++p) {
      int idx = tid + p * 256;
      int row = idx >> 3, ko = (idx & 7) * 8;
      u16x8 v = (u16x8)(unsigned short)0;
      if (r0 + row < N_NODES) v = *(const u16x8*)&Zb[(size_t)(r0 + row) * HD + k0 + ko];
      *(u16x8*)&As[row][ko] = v;
    }
#pragma unroll
    for (int p = 0; p < 6; ++p) {
      int idx = tid + p * 256;
      int col = idx >> 3, ko = (idx & 7) * 8;
      u16x8 v = (col < 128) ? *(const u16x8*)&W1T[(size_t)col * HD + k0 + ko]
                            : *(const u16x8*)&WoutT[(size_t)(col - 128) * HD + k0 + ko];
      *(u16x8*)&Bs[col][ko] = v;
    }
    __syncthreads();
#pragma unroll
    for (int kk = 0; kk < 64; kk += 32) {
      bf16x8 a = *(const bf16x8*)&As[w * 16 + cl][kk + kg * 8];
#pragma unroll
      for (int ct = 0; ct < 12; ++ct) {
        bf16x8 b = *(const bf16x8*)&Bs[ct * 16 + cl][kk + kg * 8];
        acc[ct] = __builtin_amdgcn_mfma_f32_16x16x32_bf16(a, b, acc[ct], 0, 0, 0);
      }
    }
    __syncthreads();
  }
  // semantic epilogue (cols 0..127)
  float rs[4] = {0.f, 0.f, 0.f, 0.f};
#pragma unroll
  for (int ct = 0; ct < 8; ++ct) {
    int col = ct * 16 + cl;
    float bb = b1[col], qq = qv[col];
#pragma unroll
    for (int reg = 0; reg < 4; ++reg) rs[reg] += tanhf(acc[ct][reg] + bb) * qq;
  }
#pragma unroll
  for (int off = 1; off < 16; off <<= 1)
#pragma unroll
    for (int reg = 0; reg < 4; ++reg) rs[reg] += __shfl_xor(rs[reg], off);
  float val = 0.f;
#pragma unroll
  for (int reg = 0; reg < 4; ++reg) {
    int row = r0 + w * 16 + kg * 4 + reg;
    if (row < N_NODES) val += rs[reg];
  }
  if (cl == 0) redv[w * 4 + kg] = val;
  __syncthreads();
  if (tid == 0) {
    float sv = 0.f;
#pragma unroll
    for (int k = 0; k < 16; ++k) sv += redv[k];
    atomicAdd(wsem_m, sv);
  }
  // y epilogue (cols 128..191), bf16
#pragma unroll
  for (int ct = 8; ct < 12; ++ct)
#pragma unroll
    for (int reg = 0; reg < 4; ++reg) {
      int row = r0 + w * 16 + kg * 4 + reg;
      if (row < N_NODES) yb[(size_t)row * OUT_DIM + (ct - 8) * 16 + cl] = f2b(acc[ct][reg]);
    }
}

// ---- beta = softmax(wsem / N) ----
__global__ void k_beta(const float* __restrict__ wsem, float* __restrict__ beta) {
  float w0 = wsem[0] / (float)N_NODES, w1 = wsem[1] / (float)N_NODES;
  float mx = fmaxf(w0, w1);
  float e0 = expf(w0 - mx), e1 = expf(w1 - mx);
  float inv = 1.f / (e0 + e1);
  beta[0] = e0 * inv;
  beta[1] = e1 * inv;
}

// ---- final: out = beta0*y0 + beta1*y1 + bout ----
__global__ void k_final(const unsigned short* __restrict__ yb, const float* __restrict__ beta,
                        const float* __restrict__ bout, float* __restrict__ out) {
  int gid = blockIdx.x * blockDim.x + threadIdx.x;
  size_t off = (size_t)gid * 8;
  if (off >= (size_t)N_NODES * OUT_DIM) return;
  u16x8 ya = *(const u16x8*)&yb[off];
  u16x8 yc = *(const u16x8*)&yb[(size_t)N_NODES * OUT_DIM + off];
  float b0 = beta[0], b1v = beta[1];
  const int cb = (int)(off & 63);
#pragma unroll
  for (int j = 0; j < 8; ++j)
    out[off + j] = b0 * b2f(ya[j]) + b1v * b2f(yc[j]) + bout[cb + j];
}

extern "C" void kernel_launch(void* const* d_in, const int* in_sizes, int n_in,
                              void* d_out, int out_size, void* d_ws, size_t ws_size,
                              hipStream_t stream) {
  const float* x    = (const float*)d_in[0];
  const int*   src  = (const int*)d_in[1];
  const int*   dst  = (const int*)d_in[2];
  const float* Wg   = (const float*)d_in[3];
  const float* al   = (const float*)d_in[4];
  const float* ar   = (const float*)d_in[5];
  const float* bg   = (const float*)d_in[6];
  const float* W1   = (const float*)d_in[7];
  const float* b1   = (const float*)d_in[8];
  const float* q    = (const float*)d_in[9];
  const float* Wout = (const float*)d_in[10];
  const float* bout = (const float*)d_in[11];
  float* out = (float*)d_out;

  // workspace layout (bytes, 64B aligned); total ~132.1 MB
  char* ws = (char*)d_ws;
  unsigned short* featb = (unsigned short*)(ws);                 // 51,200,000
  unsigned short* z     = (unsigned short*)(ws + 51200000);      // 51,200,000
  unsigned short* yb    = (unsigned short*)(ws + 102400000);     // 12,800,000 (bf16 [2][N][64])
  int* ell_src          = (int*)(ws + 115200000);                // 12,800,000
  float* el             = (float*)(ws + 128000000);              //  1,600,000
  float* er             = (float*)(ws + 129600000);              //  1,600,000
  int* deg              = (int*)(ws + 131200000);                //    200,000
  unsigned short* WgbT  = (unsigned short*)(ws + 131400064);     //    524,288
  unsigned short* W1T   = (unsigned short*)(ws + 131924352);     //    131,072
  unsigned short* WoutT = (unsigned short*)(ws + 132055424);     //     65,536
  float* wsem           = (float*)(ws + 132120960);              //         64
  float* beta           = (float*)(ws + 132121024);              //         64

  hipMemsetAsync(wsem, 0, 2 * sizeof(float), stream);
  k_prep<<<1408, 256, 0, stream>>>(Wg, W1, Wout, WgbT, W1T, WoutT);

  for (int m = 0; m < M_PATHS; ++m) {
    const int* srcm = src + (size_t)m * E_EDGES;
    const int* dstm = dst + (size_t)m * E_EDGES;
    hipMemsetAsync(deg, 0, N_NODES * sizeof(int), stream);
    k_edge_e<<<3125, 256, 0, stream>>>(srcm, dstm, deg, ell_src);
    dim3 gf(782, 2);
    k_gemm_feat<<<gf, 256, 0, stream>>>(x, WgbT + (size_t)m * 131072,
                                        al + m * HD, ar + m * HD, featb, el, er);
    k_agg<<<12500, 256, 0, stream>>>(featb, el, er, ell_src, deg, bg + m * HD, z);
    k_gemm_post<<<782, 256, 0, stream>>>(z, W1T, WoutT, b1, q, wsem + m,
                                         yb + (size_t)m * N_NODES * OUT_DIM);
  }
  k_beta<<<1, 1, 0, stream>>>(wsem, beta);
  k_final<<<1563, 256, 0, stream>>>(yb, beta, bout, out);
}